// Round 3
// baseline (321.942 us; speedup 1.0000x reference)
//
#include <hip/hip_runtime.h>
#include <stdint.h>

#define BB 16
#define HH 512
#define WW 512
#define HWsz (HH*WW)

// exact left-to-right f32, no fma contraction: matches np's 0.299*r + 0.587*g + 0.114*b
__device__ __forceinline__ float grayf(float r,float g,float b){
  return __fadd_rn(__fadd_rn(__fmul_rn(0.299f,r),__fmul_rn(0.587f,g)),__fmul_rn(0.114f,b));
}
__device__ __forceinline__ float sigmoidf_(float x){ return 1.0f/(1.0f+expf(-x)); }

// ---------------- K0: zero the tiny ws region ----------------
__global__ void k_init(float* sums, int* maxc){
  int t = threadIdx.x;
  if(t < BB*3) sums[t] = 0.0f;
  if(t < BB) maxc[t] = 0;
}

// ---------------- K1: per-image reductions (yuv sums + max LBP code) ----
__global__ __launch_bounds__(256) void k_reduce(const float* __restrict__ frame,
     float* __restrict__ sums, int* __restrict__ maxc){
  const int b = blockIdx.z;
  const int tx0 = blockIdx.x*32, ty0 = blockIdx.y*32;
  const float* fr = frame + (size_t)b*3*HWsz;
  const int tid = threadIdx.x;
  __shared__ float sg[34][35];
  for(int i=tid;i<34*34;i+=256){
    int ly=i/34, lx=i%34;
    int gy=min(max(ty0-1+ly,0),HH-1);
    int gx=min(max(tx0-1+lx,0),WW-1);
    sg[ly][lx]=grayf(fr[gy*WW+gx],fr[HWsz+gy*WW+gx],fr[2*HWsz+gy*WW+gx]);
  }
  __syncthreads();
  const int tx=tid&31, tyb=tid>>5;
  float sy=0.f,su=0.f,sv=0.f; int cm=0;
  constexpr int dy[8]={-1,-1,0,1,1,1,0,-1};
  constexpr int dx[8]={0,1,1,1,0,-1,-1,-1};
  for(int k=0;k<4;k++){
    int row=tyb+8*k;
    int gy=ty0+row, gx=tx0+tx;
    float c = sg[row+1][tx+1];
    int bits[8];
    #pragma unroll
    for(int o=0;o<8;o++) bits[o] = (sg[row+1+dy[o]][tx+1+dx[o]] >= c) ? 1:0;
    int s=0, tr=0;
    #pragma unroll
    for(int o=0;o<8;o++){ s+=bits[o]; tr += (bits[o]!=bits[(o+7)&7]) ? 1:0; }
    int code = (tr<=2)? s : 9;
    cm = max(cm, code);
    float r=fr[gy*WW+gx], g=fr[HWsz+gy*WW+gx], bl=fr[2*HWsz+gy*WW+gx];
    sy += c;
    su += -0.147f*r - 0.289f*g + 0.436f*bl;
    sv +=  0.615f*r - 0.515f*g - 0.1f*bl;
  }
  __shared__ float ry[256], ru[256], rv[256];
  __shared__ int   rc[256];
  ry[tid]=sy; ru[tid]=su; rv[tid]=sv; rc[tid]=cm;
  __syncthreads();
  for(int s2=128;s2>0;s2>>=1){
    if(tid<s2){
      ry[tid]+=ry[tid+s2];
      ru[tid]+=ru[tid+s2];
      rv[tid]+=rv[tid+s2];
      rc[tid]=max(rc[tid],rc[tid+s2]);
    }
    __syncthreads();
  }
  if(tid==0){
    atomicAdd(&sums[b*3+0], ry[0]);
    atomicAdd(&sums[b*3+1], ru[0]);
    atomicAdd(&sums[b*3+2], rv[0]);
    atomicMax(&maxc[b], rc[0]);
  }
}

// ---------------- K2: channel-attention MLP (tiny) ----------------
__global__ void k_scale(const float* __restrict__ sums, const int* __restrict__ maxc,
    const float* __restrict__ w1, const float* __restrict__ w2,
    float* __restrict__ scale, float* __restrict__ mxf){
  int b = threadIdx.x;
  if(b >= BB) return;
  float p[3], h[3];
  for(int j=0;j<3;j++) p[j] = sums[b*3+j] * (1.0f/(float)HWsz);
  for(int i=0;i<3;i++){
    float a = p[0]*w1[i*3+0] + p[1]*w1[i*3+1] + p[2]*w1[i*3+2];
    h[i] = fmaxf(a, 0.0f);
  }
  for(int i=0;i<3;i++){
    float a = h[0]*w2[i*3+0] + h[1]*w2[i*3+1] + h[2]*w2[i*3+2];
    scale[b*3+i] = sigmoidf_(a);
  }
  mxf[b] = fmaxf((float)maxc[b], 1.0f);   // clamp: kills the only 0/0 path
}

// ---------------- K3: fused conv + mask + strength + watermark + RGB ----
__global__ __launch_bounds__(256) void k_main(const float* __restrict__ frame,
    const int* __restrict__ wm, const float* __restrict__ sa_w, const float* __restrict__ sa_b,
    const float* __restrict__ scalev, const float* __restrict__ mxf,
    float* __restrict__ out)
{
  const int b = blockIdx.z;
  const int tx0 = blockIdx.x*32, ty0 = blockIdx.y*32;
  const float* fr = frame + (size_t)b*3*HWsz;

  // sA col c holds gx = tx0 + c - 4  (c = 0..39 ALL initialized)
  // sA row r holds gy = ty0 + r - 3  (r = 0..37 ALL initialized)
  __shared__ float sA[4][38][40];  // r,g,b,lbp
  __shared__ float sg[40][41];     // gray, halo 4, edge-clamped; [gy-ty0+4][gx-tx0+4]
  __shared__ float sw[4][49];
  __shared__ float smask[32][33];
  __shared__ float sstr[4][4];
  __shared__ float ssc[8];         // 0..2 scale, 3 bias, 4 mx

  const int tid = threadIdx.x;
  if(tid < 196) sw[tid/49][tid%49] = sa_w[tid];
  if(tid >= 196 && tid < 199) ssc[tid-196] = scalev[b*3 + (tid-196)];
  if(tid == 199) ssc[3] = sa_b[0];
  if(tid == 200) ssc[4] = mxf[b];

  // gray: halo 4, edge clamp (fully initialized 40x40)
  for(int i=tid;i<40*40;i+=256){
    int ly=i/40, lx=i%40;
    int gy=min(max(ty0+ly-4,0),HH-1);
    int gx=min(max(tx0+lx-4,0),WW-1);
    sg[ly][lx]=grayf(fr[gy*WW+gx],fr[HWsz+gy*WW+gx],fr[2*HWsz+gy*WW+gx]);
  }
  // rgb: zero-pad outside image ('SAME' conv), fully initialized 38x40
  for(int i=tid;i<38*40;i+=256){
    int ly=i/40, lx=i%40;
    int gy=ty0+ly-3, gx=tx0+lx-4;
    float r=0.f,g=0.f,bl=0.f;
    if(gy>=0 && gy<HH && gx>=0 && gx<WW){
      r=fr[gy*WW+gx]; g=fr[HWsz+gy*WW+gx]; bl=fr[2*HWsz+gy*WW+gx];
    }
    sA[0][ly][lx]=r; sA[1][ly][lx]=g; sA[2][ly][lx]=bl;
  }
  __syncthreads();

  // lbp channel (zero outside image, like conv zero-padding); fully init 38x40
  {
    constexpr int dy[8]={-1,-1,0,1,1,1,0,-1};
    constexpr int dx[8]={0,1,1,1,0,-1,-1,-1};
    const float mx = ssc[4];
    for(int i=tid;i<38*40;i+=256){
      int ly=i/40, lx=i%40;
      int gy=ty0+ly-3, gx=tx0+lx-4;
      float v=0.0f;
      if(lx>=1 && lx<=38 && gy>=0 && gy<HH && gx>=0 && gx<WW){
        float c = sg[ly+1][lx];
        int bits[8];
        #pragma unroll
        for(int o=0;o<8;o++) bits[o] = (sg[ly+1+dy[o]][lx+dx[o]] >= c) ? 1:0;
        int s=0, tr=0;
        #pragma unroll
        for(int o=0;o<8;o++){ s+=bits[o]; tr += (bits[o]!=bits[(o+7)&7]) ? 1:0; }
        int code = (tr<=2)? s : 9;
        v = (float)code / mx;
      }
      sA[3][ly][lx]=v;
    }
  }
  __syncthreads();

  // 7x7x4 conv; thread = (row ty, col-group t of 4 pixels). Scalar window
  // loads: cols 4t+1 .. 4t+10, all within the initialized [0,39] range.
  const int t  = tid & 7;
  const int ty = tid >> 3;
  float a0=ssc[3], a1=ssc[3], a2=ssc[3], a3=ssc[3];
  for(int ci=0;ci<4;ci++){
    #pragma unroll
    for(int ky=0;ky<7;ky++){
      const float* rowp = &sA[ci][ty+ky][4*t];
      float win[10];
      #pragma unroll
      for(int w=0;w<10;w++) win[w]=rowp[1+w];
      const float* wr = &sw[ci][ky*7];
      #pragma unroll
      for(int kx=0;kx<7;kx++){
        float wt = wr[kx];
        a0 += win[kx+0]*wt;
        a1 += win[kx+1]*wt;
        a2 += win[kx+2]*wt;
        a3 += win[kx+3]*wt;
      }
    }
  }
  float m0=sigmoidf_(a0), m1=sigmoidf_(a1), m2=sigmoidf_(a2), m3=sigmoidf_(a3);
  smask[ty][4*t+0]=m0; smask[ty][4*t+1]=m1; smask[ty][4*t+2]=m2; smask[ty][4*t+3]=m3;
  {
    size_t midx = (size_t)(3*BB)*HWsz + (size_t)b*HWsz + (size_t)(ty0+ty)*WW + (size_t)(tx0+4*t);
    float4 mv = make_float4(m0,m1,m2,m3);
    *reinterpret_cast<float4*>(out + midx) = mv;
  }
  __syncthreads();

  // strength: mean of mask per 8x8 block
  if(tid<16){
    int rb=tid>>2, cb=tid&3;
    float ssum=0.f;
    for(int yy=0;yy<8;yy++)
      #pragma unroll
      for(int xx=0;xx<8;xx++) ssum += smask[rb*8+yy][cb*8+xx];
    sstr[rb][cb]=ssum*(1.0f/64.0f);
  }
  __syncthreads();

  // final: weighted yuv + rank-1 DCT delta -> rgb (scalar LDS reads)
  {
    const float sc0=ssc[0], sc1=ssc[1], sc2=ssc[2];
    const float strength = sstr[ty>>3][t>>1];
    const int bw = (tx0 + 4*t) >> 3;
    const float sgn = (float)(2*wm[bw]-1);
    // D[4][row%8]: 0.5*cos(pi(2j+1)/4), sign pattern + - - + + - - + (period 4)
    const float d4 = (((ty+1)&2) ? -0.35355339059327373f : 0.35355339059327373f);
    const float delta = 0.05f * strength * sgn * d4;
    const float D3tab[8] = { 0.4157348061512726f,-0.0975451610080641f,-0.4903926402016152f,-0.2777851165098011f,
                             0.2777851165098011f, 0.4903926402016152f, 0.0975451610080641f,-0.4157348061512726f };
    float4 pr, pg, pb;
    float vr[4], vg[4], vb[4];
    #pragma unroll
    for(int j=0;j<4;j++){
      float r  = sA[0][ty+3][4*t+j+4];
      float g  = sA[1][ty+3][4*t+j+4];
      float bl = sA[2][ty+3][4*t+j+4];
      float yv = (0.299f*r + 0.587f*g + 0.114f*bl) * sc0;
      float uv = (-0.147f*r - 0.289f*g + 0.436f*bl) * sc1;
      float vv = ( 0.615f*r - 0.515f*g - 0.1f*bl) * sc2;
      float ym = yv + delta * D3tab[(t&1)*4 + j];
      vr[j] = ym + 1.14f*vv;
      vg[j] = ym - 0.395f*uv - 0.581f*vv;
      vb[j] = ym + 2.032f*uv;
    }
    pr = make_float4(vr[0],vr[1],vr[2],vr[3]);
    pg = make_float4(vg[0],vg[1],vg[2],vg[3]);
    pb = make_float4(vb[0],vb[1],vb[2],vb[3]);
    size_t base = (size_t)(ty0+ty)*WW + (size_t)(tx0+4*t);
    *reinterpret_cast<float4*>(out + (size_t)(b*3+0)*HWsz + base) = pr;
    *reinterpret_cast<float4*>(out + (size_t)(b*3+1)*HWsz + base) = pg;
    *reinterpret_cast<float4*>(out + (size_t)(b*3+2)*HWsz + base) = pb;
  }
}

extern "C" void kernel_launch(void* const* d_in, const int* in_sizes, int n_in,
                              void* d_out, int out_size, void* d_ws, size_t ws_size,
                              hipStream_t stream) {
  const float* frame = (const float*)d_in[0];
  const int*   wmark = (const int*)d_in[1];
  const float* sa_w  = (const float*)d_in[2];
  const float* sa_b  = (const float*)d_in[3];
  const float* ca_w1 = (const float*)d_in[4];
  const float* ca_w2 = (const float*)d_in[5];
  float* out = (float*)d_out;
  char* ws = (char*)d_ws;
  float* sums  = (float*)(ws);        // 48 f32
  int*   maxc  = (int*)(ws + 192);    // 16 int
  float* scalev= (float*)(ws + 256);  // 48 f32
  float* mxf   = (float*)(ws + 448);  // 16 f32

  hipLaunchKernelGGL(k_init,  dim3(1),        dim3(64),  0, stream, sums, maxc);
  hipLaunchKernelGGL(k_reduce,dim3(16,16,16), dim3(256), 0, stream, frame, sums, maxc);
  hipLaunchKernelGGL(k_scale, dim3(1),        dim3(64),  0, stream, sums, maxc, ca_w1, ca_w2, scalev, mxf);
  hipLaunchKernelGGL(k_main,  dim3(16,16,16), dim3(256), 0, stream, frame, wmark, sa_w, sa_b, scalev, mxf, out);
}

// Round 5
// 226.279 us; speedup vs baseline: 1.4228x; 1.4228x over previous
//
#include <hip/hip_runtime.h>
#include <stdint.h>

#define BB 16
#define HH 512
#define WW 512
#define HWsz (HH*WW)

// exact left-to-right f32, no fma contraction: matches np's 0.299*r + 0.587*g + 0.114*b
__device__ __forceinline__ float grayf(float r,float g,float b){
  return __fadd_rn(__fadd_rn(__fmul_rn(0.299f,r),__fmul_rn(0.587f,g)),__fmul_rn(0.114f,b));
}
__device__ __forceinline__ float sigmoidf_(float x){ return 1.0f/(1.0f+expf(-x)); }

// offs order: (-1,0),(-1,1),(0,1),(1,1),(1,0),(1,-1),(0,-1),(-1,-1)
__device__ __forceinline__ int lbp_code(float tl,float tc,float tr,
                                        float ml,float c ,float mr,
                                        float bl,float bc,float br){
  int b0 = tc>=c, b1 = tr>=c, b2 = mr>=c, b3 = br>=c;
  int b4 = bc>=c, b5 = bl>=c, b6 = ml>=c, b7 = tl>=c;
  int s = (b0+b1)+(b2+b3)+(b4+b5)+(b6+b7);
  int tr_ = (b0!=b7)+(b1!=b0)+(b2!=b1)+(b3!=b2)+(b4!=b3)+(b5!=b4)+(b6!=b5)+(b7!=b6);
  return (tr_<=2)? s : 9;
}

// ---------------- K0: zero the tiny ws region ----------------
__global__ void k_init(float* sums, int* maxc){
  int t = threadIdx.x;
  if(t < BB*3) sums[t] = 0.0f;
  if(t < BB) maxc[t] = 0;
}

// ---------------- K1: per-image reductions (yuv sums + max LBP code) ----
// 1024 blocks: image b = blk>>6, strip s = blk&63 (8 rows). Full-width strips,
// float4 staging, each pixel read exactly once.
#define RSTRIDE 520   // 512 + halo cols
__global__ __launch_bounds__(256,4) void k_reduce(const float* __restrict__ frame,
     float* __restrict__ sums, int* __restrict__ maxc){
  const int blk = blockIdx.x;
  const int b = blk >> 6;
  const int s = blk & 63;
  const int r0 = s*8;
  const float4* F = (const float4*)(frame + (size_t)b*3*HWsz);
  __shared__ float sg[10*RSTRIDE];   // row R=0..9 <-> gy=r0-1+R (clamped); phys col = x+4
  const int tid = threadIdx.x;
  float sy=0.f, su=0.f, sv=0.f;
  #pragma unroll
  for(int k=0;k<5;k++){
    int j = tid + 256*k;            // exactly 1280 = 10 rows * 128 float4
    int row = j >> 7;
    int c4  = j & 127;
    int gy  = min(max(r0-1+row,0),HH-1);
    int fi  = gy*128 + c4;
    float4 r4 = F[fi];
    float4 g4 = F[65536  + fi];
    float4 b4 = F[131072 + fi];
    float4 gr;
    gr.x = grayf(r4.x,g4.x,b4.x);
    gr.y = grayf(r4.y,g4.y,b4.y);
    gr.z = grayf(r4.z,g4.z,b4.z);
    gr.w = grayf(r4.w,g4.w,b4.w);
    *(float4*)&sg[row*RSTRIDE + 4 + 4*c4] = gr;
    if(c4==0)   sg[row*RSTRIDE + 3]   = gr.x;   // x=-1 clamp
    if(c4==127) sg[row*RSTRIDE + 516] = gr.w;   // x=512 clamp
    if(row>=1 && row<=8){                        // interior rows only (no double count)
      sy += (gr.x+gr.y)+(gr.z+gr.w);
      float rs_=(r4.x+r4.y)+(r4.z+r4.w), gs_=(g4.x+g4.y)+(g4.z+g4.w), bs_=(b4.x+b4.y)+(b4.z+b4.w);
      su += -0.147f*rs_ - 0.289f*gs_ + 0.436f*bs_;
      sv +=  0.615f*rs_ - 0.515f*gs_ - 0.1f*bs_;
    }
  }
  __syncthreads();
  // LBP: thread t handles cols x in {2t, 2t+1}, rows gy = r0..r0+7 (R=1..8).
  int cm = 0;
  {
    const float* base = sg + (2*tid + 3);  // phys col of x=2t-1
    float t0=base[0], t1=base[1], t2=base[2], t3=base[3];
    float m0=base[RSTRIDE], m1=base[RSTRIDE+1], m2=base[RSTRIDE+2], m3=base[RSTRIDE+3];
    #pragma unroll
    for(int R=1;R<=8;R++){
      const float* brow = base + (R+1)*RSTRIDE;
      float b0=brow[0], b1=brow[1], b2=brow[2], b3=brow[3];
      cm = max(cm, lbp_code(t0,t1,t2, m0,m1,m2, b0,b1,b2));
      cm = max(cm, lbp_code(t1,t2,t3, m1,m2,m3, b1,b2,b3));
      t0=m0;t1=m1;t2=m2;t3=m3; m0=b0;m1=b1;m2=b2;m3=b3;
    }
  }
  #pragma unroll
  for(int off=32;off>=1;off>>=1){
    sy += __shfl_down(sy,off,64);
    su += __shfl_down(su,off,64);
    sv += __shfl_down(sv,off,64);
    cm = max(cm,__shfl_down(cm,off,64));
  }
  __shared__ float rs[3][4]; __shared__ int rm[4];
  int wave=tid>>6, lane=tid&63;
  if(lane==0){ rs[0][wave]=sy; rs[1][wave]=su; rs[2][wave]=sv; rm[wave]=cm; }
  __syncthreads();
  if(tid==0){
    atomicAdd(&sums[b*3+0], (rs[0][0]+rs[0][1])+(rs[0][2]+rs[0][3]));
    atomicAdd(&sums[b*3+1], (rs[1][0]+rs[1][1])+(rs[1][2]+rs[1][3]));
    atomicAdd(&sums[b*3+2], (rs[2][0]+rs[2][1])+(rs[2][2]+rs[2][3]));
    atomicMax(&maxc[b], max(max(rm[0],rm[1]),max(rm[2],rm[3])));
  }
}

// ---------------- K2: channel-attention MLP (tiny) ----------------
__global__ void k_scale(const float* __restrict__ sums, const int* __restrict__ maxc,
    const float* __restrict__ w1, const float* __restrict__ w2,
    float* __restrict__ scale, float* __restrict__ mxf){
  int b = threadIdx.x;
  if(b >= BB) return;
  float p[3], h[3];
  for(int j=0;j<3;j++) p[j] = sums[b*3+j] * (1.0f/(float)HWsz);
  for(int i=0;i<3;i++){
    float a = p[0]*w1[i*3+0] + p[1]*w1[i*3+1] + p[2]*w1[i*3+2];
    h[i] = fmaxf(a, 0.0f);
  }
  for(int i=0;i<3;i++){
    float a = h[0]*w2[i*3+0] + h[1]*w2[i*3+1] + h[2]*w2[i*3+2];
    scale[b*3+i] = sigmoidf_(a);
  }
  mxf[b] = fmaxf((float)maxc[b], 1.0f);
}

// ---------------- K3: fused conv + mask + strength + watermark + RGB ----
// ROUND-2 VERSION VERBATIM (the exact code that passed) — bisect control.
__global__ __launch_bounds__(256) void k_main(const float* __restrict__ frame,
    const int* __restrict__ wm, const float* __restrict__ sa_w, const float* __restrict__ sa_b,
    const float* __restrict__ scalev, const float* __restrict__ mxf,
    float* __restrict__ out)
{
  const int b = blockIdx.z;
  const int tx0 = blockIdx.x*32, ty0 = blockIdx.y*32;
  const float* fr = frame + (size_t)b*3*HWsz;

  __shared__ float sA[4][38][40];  // r,g,b,lbp
  __shared__ float sg[40][41];     // gray, halo 4, edge-clamped
  __shared__ float sw[4][49];
  __shared__ float smask[32][33];
  __shared__ float sstr[4][4];
  __shared__ float ssc[8];         // 0..2 scale, 3 bias, 4 mx

  const int tid = threadIdx.x;
  if(tid < 196) sw[tid/49][tid%49] = sa_w[tid];
  if(tid >= 196 && tid < 199) ssc[tid-196] = scalev[b*3 + (tid-196)];
  if(tid == 199) ssc[3] = sa_b[0];
  if(tid == 200) ssc[4] = mxf[b];

  // gray: halo 4, edge clamp (fully initialized 40x40)
  for(int i=tid;i<40*40;i+=256){
    int ly=i/40, lx=i%40;
    int gy=min(max(ty0+ly-4,0),HH-1);
    int gx=min(max(tx0+lx-4,0),WW-1);
    sg[ly][lx]=grayf(fr[gy*WW+gx],fr[HWsz+gy*WW+gx],fr[2*HWsz+gy*WW+gx]);
  }
  // rgb: zero-pad outside image ('SAME' conv), fully initialized 38x40
  for(int i=tid;i<38*40;i+=256){
    int ly=i/40, lx=i%40;
    int gy=ty0+ly-3, gx=tx0+lx-4;
    float r=0.f,g=0.f,bl=0.f;
    if(gy>=0 && gy<HH && gx>=0 && gx<WW){
      r=fr[gy*WW+gx]; g=fr[HWsz+gy*WW+gx]; bl=fr[2*HWsz+gy*WW+gx];
    }
    sA[0][ly][lx]=r; sA[1][ly][lx]=g; sA[2][ly][lx]=bl;
  }
  __syncthreads();

  // lbp channel (zero outside image, like conv zero-padding)
  {
    constexpr int dy[8]={-1,-1,0,1,1,1,0,-1};
    constexpr int dx[8]={0,1,1,1,0,-1,-1,-1};
    const float mx = ssc[4];
    for(int i=tid;i<38*40;i+=256){
      int ly=i/40, lx=i%40;
      int gy=ty0+ly-3, gx=tx0+lx-4;
      float v = 0.0f;
      if(lx>=1 && lx<=38 && gy>=0 && gy<HH && gx>=0 && gx<WW){
        float c = sg[ly+1][lx];
        int bits[8];
        #pragma unroll
        for(int o=0;o<8;o++) bits[o] = (sg[ly+1+dy[o]][lx+dx[o]] >= c) ? 1:0;
        int s=0, tr=0;
        #pragma unroll
        for(int o=0;o<8;o++){ s+=bits[o]; tr += (bits[o]!=bits[(o+7)&7]) ? 1:0; }
        int code = (tr<=2)? s : 9;
        v = (float)code / mx;
      }
      sA[3][ly][lx]=v;
    }
  }
  __syncthreads();

  // 7x7x4 conv; thread = (row ty, col-group t of 4 pixels). Scalar window loads.
  const int t  = tid & 7;
  const int ty = tid >> 3;
  float a0=ssc[3], a1=ssc[3], a2=ssc[3], a3=ssc[3];
  for(int ci=0;ci<4;ci++){
    #pragma unroll
    for(int ky=0;ky<7;ky++){
      const float* rowp = &sA[ci][ty+ky][4*t];
      float win[10];
      #pragma unroll
      for(int w=0;w<10;w++) win[w]=rowp[1+w];
      const float* wr = &sw[ci][ky*7];
      #pragma unroll
      for(int kx=0;kx<7;kx++){
        float wt = wr[kx];
        a0 += win[kx+0]*wt;
        a1 += win[kx+1]*wt;
        a2 += win[kx+2]*wt;
        a3 += win[kx+3]*wt;
      }
    }
  }
  float m0=sigmoidf_(a0), m1=sigmoidf_(a1), m2=sigmoidf_(a2), m3=sigmoidf_(a3);
  smask[ty][4*t+0]=m0; smask[ty][4*t+1]=m1; smask[ty][4*t+2]=m2; smask[ty][4*t+3]=m3;
  {
    size_t midx = (size_t)(3*BB)*HWsz + (size_t)b*HWsz + (size_t)(ty0+ty)*WW + (size_t)(tx0+4*t);
    *reinterpret_cast<float4*>(out + midx) = make_float4(m0,m1,m2,m3);
  }
  __syncthreads();

  // strength: mean of mask per 8x8 block
  if(tid<16){
    int rb=tid>>2, cb=tid&3;
    float ssum=0.f;
    for(int yy=0;yy<8;yy++)
      #pragma unroll
      for(int xx=0;xx<8;xx++) ssum += smask[rb*8+yy][cb*8+xx];
    sstr[rb][cb]=ssum*(1.0f/64.0f);
  }
  __syncthreads();

  // final: weighted yuv + rank-1 DCT delta -> rgb (scalar LDS reads)
  {
    const float sc0=ssc[0], sc1=ssc[1], sc2=ssc[2];
    const float strength = sstr[ty>>3][t>>1];
    const int bw = (tx0 + 4*t) >> 3;
    const float sgn = (float)(2*wm[bw]-1);
    const float d4 = (((ty+1)&2) ? -0.35355339059327373f : 0.35355339059327373f);
    const float delta = 0.05f * strength * sgn * d4;
    const float D3tab[8] = { 0.4157348061512726f,-0.0975451610080641f,-0.4903926402016152f,-0.2777851165098011f,
                             0.2777851165098011f, 0.4903926402016152f, 0.0975451610080641f,-0.4157348061512726f };
    float vr[4], vg[4], vb[4];
    #pragma unroll
    for(int j=0;j<4;j++){
      float r  = sA[0][ty+3][4*t+j+4];
      float g  = sA[1][ty+3][4*t+j+4];
      float bl = sA[2][ty+3][4*t+j+4];
      float yv = (0.299f*r + 0.587f*g + 0.114f*bl) * sc0;
      float uv = (-0.147f*r - 0.289f*g + 0.436f*bl) * sc1;
      float vv = ( 0.615f*r - 0.515f*g - 0.1f*bl) * sc2;
      float ym = yv + delta * D3tab[(t&1)*4 + j];
      vr[j] = ym + 1.14f*vv;
      vg[j] = ym - 0.395f*uv - 0.581f*vv;
      vb[j] = ym + 2.032f*uv;
    }
    size_t base = (size_t)(ty0+ty)*WW + (size_t)(tx0+4*t);
    *reinterpret_cast<float4*>(out + (size_t)(b*3+0)*HWsz + base) = make_float4(vr[0],vr[1],vr[2],vr[3]);
    *reinterpret_cast<float4*>(out + (size_t)(b*3+1)*HWsz + base) = make_float4(vg[0],vg[1],vg[2],vg[3]);
    *reinterpret_cast<float4*>(out + (size_t)(b*3+2)*HWsz + base) = make_float4(vb[0],vb[1],vb[2],vb[3]);
  }
}

extern "C" void kernel_launch(void* const* d_in, const int* in_sizes, int n_in,
                              void* d_out, int out_size, void* d_ws, size_t ws_size,
                              hipStream_t stream) {
  const float* frame = (const float*)d_in[0];
  const int*   wmark = (const int*)d_in[1];
  const float* sa_w  = (const float*)d_in[2];
  const float* sa_b  = (const float*)d_in[3];
  const float* ca_w1 = (const float*)d_in[4];
  const float* ca_w2 = (const float*)d_in[5];
  float* out = (float*)d_out;
  char* ws = (char*)d_ws;
  float* sums  = (float*)(ws);        // 48 f32
  int*   maxc  = (int*)(ws + 192);    // 16 int
  float* scalev= (float*)(ws + 256);  // 48 f32
  float* mxf   = (float*)(ws + 448);  // 16 f32

  hipLaunchKernelGGL(k_init,  dim3(1),        dim3(64),  0, stream, sums, maxc);
  hipLaunchKernelGGL(k_reduce,dim3(1024),     dim3(256), 0, stream, frame, sums, maxc);
  hipLaunchKernelGGL(k_scale, dim3(1),        dim3(64),  0, stream, sums, maxc, ca_w1, ca_w2, scalev, mxf);
  hipLaunchKernelGGL(k_main,  dim3(16,16,16), dim3(256), 0, stream, frame, wmark, sa_w, sa_b, scalev, mxf, out);
}

// Round 7
// 194.395 us; speedup vs baseline: 1.6561x; 1.1640x over previous
//
#include <hip/hip_runtime.h>
#include <stdint.h>

#define BB 16
#define HH 512
#define WW 512
#define HWsz (HH*WW)

// exact left-to-right f32, no fma contraction: matches np's 0.299*r + 0.587*g + 0.114*b
__device__ __forceinline__ float grayf(float r,float g,float b){
  return __fadd_rn(__fadd_rn(__fmul_rn(0.299f,r),__fmul_rn(0.587f,g)),__fmul_rn(0.114f,b));
}
__device__ __forceinline__ float sigmoidf_(float x){ return 1.0f/(1.0f+expf(-x)); }

// offs order: (-1,0),(-1,1),(0,1),(1,1),(1,0),(1,-1),(0,-1),(-1,-1)
__device__ __forceinline__ int lbp_code(float tl,float tc,float tr,
                                        float ml,float c ,float mr,
                                        float bl,float bc,float br){
  int b0 = tc>=c, b1 = tr>=c, b2 = mr>=c, b3 = br>=c;
  int b4 = bc>=c, b5 = bl>=c, b6 = ml>=c, b7 = tl>=c;
  int s = (b0+b1)+(b2+b3)+(b4+b5)+(b6+b7);
  int tr_ = (b0!=b7)+(b1!=b0)+(b2!=b1)+(b3!=b2)+(b4!=b3)+(b5!=b4)+(b6!=b5)+(b7!=b6);
  return (tr_<=2)? s : 9;
}

// ---------------- K0: zero the tiny ws region ----------------
__global__ void k_init(float* sums, int* maxc){
  int t = threadIdx.x;
  if(t < BB*3) sums[t] = 0.0f;
  if(t < BB) maxc[t] = 0;
}

// ---------------- K1: per-image reductions (yuv sums + max LBP code) ----
// (unchanged — validated in round 5)
#define RSTRIDE 520
__global__ __launch_bounds__(256,4) void k_reduce(const float* __restrict__ frame,
     float* __restrict__ sums, int* __restrict__ maxc){
  const int blk = blockIdx.x;
  const int b = blk >> 6;
  const int s = blk & 63;
  const int r0 = s*8;
  const float4* F = (const float4*)(frame + (size_t)b*3*HWsz);
  __shared__ float sg[10*RSTRIDE];
  const int tid = threadIdx.x;
  float sy=0.f, su=0.f, sv=0.f;
  #pragma unroll
  for(int k=0;k<5;k++){
    int j = tid + 256*k;
    int row = j >> 7;
    int c4  = j & 127;
    int gy  = min(max(r0-1+row,0),HH-1);
    int fi  = gy*128 + c4;
    float4 r4 = F[fi];
    float4 g4 = F[65536  + fi];
    float4 b4 = F[131072 + fi];
    float4 gr;
    gr.x = grayf(r4.x,g4.x,b4.x);
    gr.y = grayf(r4.y,g4.y,b4.y);
    gr.z = grayf(r4.z,g4.z,b4.z);
    gr.w = grayf(r4.w,g4.w,b4.w);
    *(float4*)&sg[row*RSTRIDE + 4 + 4*c4] = gr;
    if(c4==0)   sg[row*RSTRIDE + 3]   = gr.x;
    if(c4==127) sg[row*RSTRIDE + 516] = gr.w;
    if(row>=1 && row<=8){
      sy += (gr.x+gr.y)+(gr.z+gr.w);
      float rs_=(r4.x+r4.y)+(r4.z+r4.w), gs_=(g4.x+g4.y)+(g4.z+g4.w), bs_=(b4.x+b4.y)+(b4.z+b4.w);
      su += -0.147f*rs_ - 0.289f*gs_ + 0.436f*bs_;
      sv +=  0.615f*rs_ - 0.515f*gs_ - 0.1f*bs_;
    }
  }
  __syncthreads();
  int cm = 0;
  {
    const float* base = sg + (2*tid + 3);
    float t0=base[0], t1=base[1], t2=base[2], t3=base[3];
    float m0=base[RSTRIDE], m1=base[RSTRIDE+1], m2=base[RSTRIDE+2], m3=base[RSTRIDE+3];
    #pragma unroll
    for(int R=1;R<=8;R++){
      const float* brow = base + (R+1)*RSTRIDE;
      float b0=brow[0], b1=brow[1], b2=brow[2], b3=brow[3];
      cm = max(cm, lbp_code(t0,t1,t2, m0,m1,m2, b0,b1,b2));
      cm = max(cm, lbp_code(t1,t2,t3, m1,m2,m3, b1,b2,b3));
      t0=m0;t1=m1;t2=m2;t3=m3; m0=b0;m1=b1;m2=b2;m3=b3;
    }
  }
  #pragma unroll
  for(int off=32;off>=1;off>>=1){
    sy += __shfl_down(sy,off,64);
    su += __shfl_down(su,off,64);
    sv += __shfl_down(sv,off,64);
    cm = max(cm,__shfl_down(cm,off,64));
  }
  __shared__ float rs[3][4]; __shared__ int rm[4];
  int wave=tid>>6, lane=tid&63;
  if(lane==0){ rs[0][wave]=sy; rs[1][wave]=su; rs[2][wave]=sv; rm[wave]=cm; }
  __syncthreads();
  if(tid==0){
    atomicAdd(&sums[b*3+0], (rs[0][0]+rs[0][1])+(rs[0][2]+rs[0][3]));
    atomicAdd(&sums[b*3+1], (rs[1][0]+rs[1][1])+(rs[1][2]+rs[1][3]));
    atomicAdd(&sums[b*3+2], (rs[2][0]+rs[2][1])+(rs[2][2]+rs[2][3]));
    atomicMax(&maxc[b], max(max(rm[0],rm[1]),max(rm[2],rm[3])));
  }
}

// ---------------- K2: channel-attention MLP (tiny) ----------------
__global__ void k_scale(const float* __restrict__ sums, const int* __restrict__ maxc,
    const float* __restrict__ w1, const float* __restrict__ w2,
    float* __restrict__ scale, float* __restrict__ mxf){
  int b = threadIdx.x;
  if(b >= BB) return;
  float p[3], h[3];
  for(int j=0;j<3;j++) p[j] = sums[b*3+j] * (1.0f/(float)HWsz);
  for(int i=0;i<3;i++){
    float a = p[0]*w1[i*3+0] + p[1]*w1[i*3+1] + p[2]*w1[i*3+2];
    h[i] = fmaxf(a, 0.0f);
  }
  for(int i=0;i<3;i++){
    float a = h[0]*w2[i*3+0] + h[1]*w2[i*3+1] + h[2]*w2[i*3+2];
    scale[b*3+i] = sigmoidf_(a);
  }
  mxf[b] = fmaxf((float)maxc[b], 1.0f);
}

// ---------------- K3: fused conv + mask + strength + watermark + RGB ----
// ROUND-4 PASSING BODY VERBATIM. Single delta: sA inner dim 40 -> 43
// (physical LDS layout only; sA is accessed ONLY with scalar ops, so this
// cannot change semantics). 43 = 3 mod 4 -> conv-read bank spread becomes
// exact 2-way (free) instead of 8-way.
__global__ __launch_bounds__(256) void k_main(const float* __restrict__ frame,
    const int* __restrict__ wm, const float* __restrict__ sa_w, const float* __restrict__ sa_b,
    const float* __restrict__ scalev, const float* __restrict__ mxf,
    float* __restrict__ out)
{
  const int b = blockIdx.z;
  const int tx0 = blockIdx.x*32, ty0 = blockIdx.y*32;
  const float* fr = frame + (size_t)b*3*HWsz;

  __shared__ float sA[4][38][43];  // r,g,b,lbp  (cols 0..39 used; 40..42 pad)
  __shared__ float sg[40][41];     // gray, halo 4, edge-clamped
  __shared__ float sw[4][49];
  __shared__ float smask[32][33];
  __shared__ float sstr[4][4];
  __shared__ float ssc[8];         // 0..2 scale, 3 bias, 4 mx

  const int tid = threadIdx.x;
  if(tid < 196) sw[tid/49][tid%49] = sa_w[tid];
  if(tid >= 196 && tid < 199) ssc[tid-196] = scalev[b*3 + (tid-196)];
  if(tid == 199) ssc[3] = sa_b[0];
  if(tid == 200) ssc[4] = mxf[b];

  // gray: halo 4, edge clamp (fully initialized 40x40)
  for(int i=tid;i<40*40;i+=256){
    int ly=i/40, lx=i%40;
    int gy=min(max(ty0+ly-4,0),HH-1);
    int gx=min(max(tx0+lx-4,0),WW-1);
    sg[ly][lx]=grayf(fr[gy*WW+gx],fr[HWsz+gy*WW+gx],fr[2*HWsz+gy*WW+gx]);
  }
  // rgb: zero-pad outside image ('SAME' conv), fully initialized 38x40
  for(int i=tid;i<38*40;i+=256){
    int ly=i/40, lx=i%40;
    int gy=ty0+ly-3, gx=tx0+lx-4;
    float r=0.f,g=0.f,bl=0.f;
    if(gy>=0 && gy<HH && gx>=0 && gx<WW){
      r=fr[gy*WW+gx]; g=fr[HWsz+gy*WW+gx]; bl=fr[2*HWsz+gy*WW+gx];
    }
    sA[0][ly][lx]=r; sA[1][ly][lx]=g; sA[2][ly][lx]=bl;
  }
  __syncthreads();

  // lbp channel (zero outside image, like conv zero-padding)
  {
    constexpr int dy[8]={-1,-1,0,1,1,1,0,-1};
    constexpr int dx[8]={0,1,1,1,0,-1,-1,-1};
    const float mx = ssc[4];
    for(int i=tid;i<38*40;i+=256){
      int ly=i/40, lx=i%40;
      int gy=ty0+ly-3, gx=tx0+lx-4;
      float v = 0.0f;
      if(lx>=1 && lx<=38 && gy>=0 && gy<HH && gx>=0 && gx<WW){
        float c = sg[ly+1][lx];
        int bits[8];
        #pragma unroll
        for(int o=0;o<8;o++) bits[o] = (sg[ly+1+dy[o]][lx+dx[o]] >= c) ? 1:0;
        int s=0, tr=0;
        #pragma unroll
        for(int o=0;o<8;o++){ s+=bits[o]; tr += (bits[o]!=bits[(o+7)&7]) ? 1:0; }
        int code = (tr<=2)? s : 9;
        v = (float)code / mx;
      }
      sA[3][ly][lx]=v;
    }
  }
  __syncthreads();

  // 7x7x4 conv; thread = (row ty, col-group t of 4 pixels). Scalar window loads.
  const int t  = tid & 7;
  const int ty = tid >> 3;
  float a0=ssc[3], a1=ssc[3], a2=ssc[3], a3=ssc[3];
  for(int ci=0;ci<4;ci++){
    #pragma unroll
    for(int ky=0;ky<7;ky++){
      const float* rowp = &sA[ci][ty+ky][4*t];
      float win[10];
      #pragma unroll
      for(int w=0;w<10;w++) win[w]=rowp[1+w];
      const float* wr = &sw[ci][ky*7];
      #pragma unroll
      for(int kx=0;kx<7;kx++){
        float wt = wr[kx];
        a0 += win[kx+0]*wt;
        a1 += win[kx+1]*wt;
        a2 += win[kx+2]*wt;
        a3 += win[kx+3]*wt;
      }
    }
  }
  float m0=sigmoidf_(a0), m1=sigmoidf_(a1), m2=sigmoidf_(a2), m3=sigmoidf_(a3);
  smask[ty][4*t+0]=m0; smask[ty][4*t+1]=m1; smask[ty][4*t+2]=m2; smask[ty][4*t+3]=m3;
  {
    size_t midx = (size_t)(3*BB)*HWsz + (size_t)b*HWsz + (size_t)(ty0+ty)*WW + (size_t)(tx0+4*t);
    *reinterpret_cast<float4*>(out + midx) = make_float4(m0,m1,m2,m3);
  }
  __syncthreads();

  // strength: mean of mask per 8x8 block
  if(tid<16){
    int rb=tid>>2, cb=tid&3;
    float ssum=0.f;
    for(int yy=0;yy<8;yy++)
      #pragma unroll
      for(int xx=0;xx<8;xx++) ssum += smask[rb*8+yy][cb*8+xx];
    sstr[rb][cb]=ssum*(1.0f/64.0f);
  }
  __syncthreads();

  // final: weighted yuv + rank-1 DCT delta -> rgb (scalar LDS reads)
  {
    const float sc0=ssc[0], sc1=ssc[1], sc2=ssc[2];
    const float strength = sstr[ty>>3][t>>1];
    const int bw = (tx0 + 4*t) >> 3;
    const float sgn = (float)(2*wm[bw]-1);
    const float d4 = (((ty+1)&2) ? -0.35355339059327373f : 0.35355339059327373f);
    const float delta = 0.05f * strength * sgn * d4;
    const float D3tab[8] = { 0.4157348061512726f,-0.0975451610080641f,-0.4903926402016152f,-0.2777851165098011f,
                             0.2777851165098011f, 0.4903926402016152f, 0.0975451610080641f,-0.4157348061512726f };
    float vr[4], vg[4], vb[4];
    #pragma unroll
    for(int j=0;j<4;j++){
      float r  = sA[0][ty+3][4*t+j+4];
      float g  = sA[1][ty+3][4*t+j+4];
      float bl = sA[2][ty+3][4*t+j+4];
      float yv = (0.299f*r + 0.587f*g + 0.114f*bl) * sc0;
      float uv = (-0.147f*r - 0.289f*g + 0.436f*bl) * sc1;
      float vv = ( 0.615f*r - 0.515f*g - 0.1f*bl) * sc2;
      float ym = yv + delta * D3tab[(t&1)*4 + j];
      vr[j] = ym + 1.14f*vv;
      vg[j] = ym - 0.395f*uv - 0.581f*vv;
      vb[j] = ym + 2.032f*uv;
    }
    size_t base = (size_t)(ty0+ty)*WW + (size_t)(tx0+4*t);
    *reinterpret_cast<float4*>(out + (size_t)(b*3+0)*HWsz + base) = make_float4(vr[0],vr[1],vr[2],vr[3]);
    *reinterpret_cast<float4*>(out + (size_t)(b*3+1)*HWsz + base) = make_float4(vg[0],vg[1],vg[2],vg[3]);
    *reinterpret_cast<float4*>(out + (size_t)(b*3+2)*HWsz + base) = make_float4(vb[0],vb[1],vb[2],vb[3]);
  }
}

extern "C" void kernel_launch(void* const* d_in, const int* in_sizes, int n_in,
                              void* d_out, int out_size, void* d_ws, size_t ws_size,
                              hipStream_t stream) {
  const float* frame = (const float*)d_in[0];
  const int*   wmark = (const int*)d_in[1];
  const float* sa_w  = (const float*)d_in[2];
  const float* sa_b  = (const float*)d_in[3];
  const float* ca_w1 = (const float*)d_in[4];
  const float* ca_w2 = (const float*)d_in[5];
  float* out = (float*)d_out;
  char* ws = (char*)d_ws;
  float* sums  = (float*)(ws);        // 48 f32
  int*   maxc  = (int*)(ws + 192);    // 16 int
  float* scalev= (float*)(ws + 256);  // 48 f32
  float* mxf   = (float*)(ws + 448);  // 16 f32

  hipLaunchKernelGGL(k_init,  dim3(1),        dim3(64),  0, stream, sums, maxc);
  hipLaunchKernelGGL(k_reduce,dim3(1024),     dim3(256), 0, stream, frame, sums, maxc);
  hipLaunchKernelGGL(k_scale, dim3(1),        dim3(64),  0, stream, sums, maxc, ca_w1, ca_w2, scalev, mxf);
  hipLaunchKernelGGL(k_main,  dim3(16,16,16), dim3(256), 0, stream, frame, wmark, sa_w, sa_b, scalev, mxf, out);
}